// Round 1
// baseline (2408.830 us; speedup 1.0000x reference)
//
#include <hip/hip_runtime.h>

#define B_ 2
#define N_ 1024
#define C_ 1024
#define H_ 16
#define HD_ 64

// ---------- wave-wide (64-lane) butterfly reductions ----------
__device__ __forceinline__ float wsumf(float x) {
#pragma unroll
  for (int off = 32; off; off >>= 1) x += __shfl_xor(x, off, 64);
  return x;
}
__device__ __forceinline__ float wmaxf(float x) {
#pragma unroll
  for (int off = 32; off; off >>= 1) x = fmaxf(x, __shfl_xor(x, off, 64));
  return x;
}
__device__ __forceinline__ int wsumi(int x) {
#pragma unroll
  for (int off = 32; off; off >>= 1) x += __shfl_xor(x, off, 64);
  return x;
}
// order-preserving float->uint map (total order matches float compare for non-NaN)
__device__ __forceinline__ unsigned orderu(float f) {
  unsigned b = __float_as_uint(f);
  return (b & 0x80000000u) ? ~b : (b | 0x80000000u);
}

// ---------- NKAT per-token factor: 1 + lc*(alpha*tanh(mean) + beta*sigmoid(var)) ----------
__global__ __launch_bounds__(64) void factor_kernel(
    const float* __restrict__ x, const float* __restrict__ alpha_p,
    const float* __restrict__ beta_p, float* __restrict__ fac) {
  const int row = blockIdx.x;  // b*N + n
  const int lane = threadIdx.x;
  const float4* xr = (const float4*)(x + (size_t)row * C_);
  float s = 0.f, ss = 0.f;
#pragma unroll
  for (int j = 0; j < 4; ++j) {
    float4 v = xr[lane + 64 * j];
    s += v.x + v.y + v.z + v.w;
    ss += v.x * v.x + v.y * v.y + v.z * v.z + v.w * v.w;
  }
  s = wsumf(s);
  ss = wsumf(ss);
  const float mean = s * (1.f / 1024.f);
  const float var = ss * (1.f / 1024.f) - mean * mean;
  const float theta =
      alpha_p[0] * tanhf(mean) + beta_p[0] * (1.f / (1.f + __expf(-var)));
  if (lane == 0) fac[row] = 1.f + 0.45125f * theta;  // lc = 0.5*0.95^2
}

// ---------- shared f32 GEMM core: 128x128 tile, 256 thr, 8x8/thread, BK=8 ----------
__device__ __forceinline__ void gemm_core(const float* __restrict__ A,
                                          const float* __restrict__ Bm, int K,
                                          int N, int m0, int n0,
                                          float* __restrict__ a_lds,
                                          float* __restrict__ b_lds,
                                          float acc[8][8]) {
  const int tid = threadIdx.x;
  const int tx = tid & 15, ty = tid >> 4;
  const int r = tid >> 1, c4 = (tid & 1) << 2;     // A tile: 128 rows x 8 cols
  const int rb = tid >> 5, cb = (tid & 31) << 2;   // B tile: 8 rows x 128 cols
  for (int k0 = 0; k0 < K; k0 += 8) {
    const float4 av = *(const float4*)(A + (size_t)(m0 + r) * K + k0 + c4);
    const float4 bv = *(const float4*)(Bm + (size_t)(k0 + rb) * N + n0 + cb);
    __syncthreads();  // previous iteration's LDS reads done
    a_lds[(c4 + 0) * 128 + r] = av.x;  // store A transposed: [k][m]
    a_lds[(c4 + 1) * 128 + r] = av.y;
    a_lds[(c4 + 2) * 128 + r] = av.z;
    a_lds[(c4 + 3) * 128 + r] = av.w;
    *(float4*)(b_lds + rb * 128 + cb) = bv;
    __syncthreads();
#pragma unroll
    for (int kk = 0; kk < 8; ++kk) {
      const float4 a0 = *(const float4*)(a_lds + kk * 128 + ty * 8);
      const float4 a1 = *(const float4*)(a_lds + kk * 128 + ty * 8 + 4);
      const float4 b0 = *(const float4*)(b_lds + kk * 128 + tx * 8);
      const float4 b1 = *(const float4*)(b_lds + kk * 128 + tx * 8 + 4);
      const float af[8] = {a0.x, a0.y, a0.z, a0.w, a1.x, a1.y, a1.z, a1.w};
      const float bf[8] = {b0.x, b0.y, b0.z, b0.w, b1.x, b1.y, b1.z, b1.w};
#pragma unroll
      for (int i = 0; i < 8; ++i)
#pragma unroll
        for (int jj = 0; jj < 8; ++jj)
          acc[i][jj] = fmaf(af[i], bf[jj], acc[i][jj]);
    }
  }
}

// ---------- qkv = x @ w_qkv, scatter into q/k/v in (B,H,N,HD) layout ----------
__global__ __launch_bounds__(256) void gemm_qkv_kernel(
    const float* __restrict__ x, const float* __restrict__ w,
    float* __restrict__ q, float* __restrict__ k, float* __restrict__ v) {
  __shared__ __align__(16) float a_lds[8 * 128];
  __shared__ __align__(16) float b_lds[8 * 128];
  float acc[8][8];
#pragma unroll
  for (int i = 0; i < 8; ++i)
#pragma unroll
    for (int jj = 0; jj < 8; ++jj) acc[i][jj] = 0.f;
  const int m0 = blockIdx.y * 128, n0 = blockIdx.x * 128;
  gemm_core(x, w, C_, 3 * C_, m0, n0, a_lds, b_lds, acc);

  const int tx = threadIdx.x & 15, ty = threadIdx.x >> 4;
  const int j0 = n0 + tx * 8;           // 8 consecutive cols: same sel, same head
  const int sel = j0 >> 10;             // 0=q 1=k 2=v
  const int hh = (j0 >> 6) & 15;
  const int d0 = j0 & 63;
  float* dstbuf = sel == 0 ? q : (sel == 1 ? k : v);
#pragma unroll
  for (int i = 0; i < 8; ++i) {
    const int mm = m0 + ty * 8 + i;
    const int bb = mm >> 10, nn = mm & 1023;
    float* dst = dstbuf + ((((size_t)bb << 4) + hh) * N_ + nn) * HD_ + d0;
    *(float4*)dst = make_float4(acc[i][0], acc[i][1], acc[i][2], acc[i][3]);
    *(float4*)(dst + 4) = make_float4(acc[i][4], acc[i][5], acc[i][6], acc[i][7]);
  }
}

// ---------- out = attn_out @ w_out + b_out ----------
__global__ __launch_bounds__(256) void gemm_out_kernel(
    const float* __restrict__ a, const float* __restrict__ w,
    const float* __restrict__ bias, float* __restrict__ out) {
  __shared__ __align__(16) float a_lds[8 * 128];
  __shared__ __align__(16) float b_lds[8 * 128];
  float acc[8][8];
#pragma unroll
  for (int i = 0; i < 8; ++i)
#pragma unroll
    for (int jj = 0; jj < 8; ++jj) acc[i][jj] = 0.f;
  const int m0 = blockIdx.y * 128, n0 = blockIdx.x * 128;
  gemm_core(a, w, C_, C_, m0, n0, a_lds, b_lds, acc);

  const int tx = threadIdx.x & 15, ty = threadIdx.x >> 4;
  const int j0 = n0 + tx * 8;
  const float4 bs0 = *(const float4*)(bias + j0);
  const float4 bs1 = *(const float4*)(bias + j0 + 4);
#pragma unroll
  for (int i = 0; i < 8; ++i) {
    const int mm = m0 + ty * 8 + i;
    float* dst = out + (size_t)mm * C_ + j0;
    *(float4*)dst = make_float4(acc[i][0] + bs0.x, acc[i][1] + bs0.y,
                                acc[i][2] + bs0.z, acc[i][3] + bs0.w);
    *(float4*)(dst + 4) = make_float4(acc[i][4] + bs1.x, acc[i][5] + bs1.y,
                                      acc[i][6] + bs1.z, acc[i][7] + bs1.w);
  }
}

// ---------- per-row attention: scores -> top-k -> top-p -> softmax*factor -> PV ----------
// one wave (64 lanes) per (b,h,q) row; scores held 16/lane in registers
__global__ __launch_bounds__(64) void attn_kernel(
    const float* __restrict__ qw, const float* __restrict__ kw,
    const float* __restrict__ vw, const float* __restrict__ fac,
    float* __restrict__ ao) {
  const int lane = threadIdx.x;
  const int row = blockIdx.x;       // bh*N + q
  const int qi = row & (N_ - 1);
  const int bh = row >> 10;
  const int b = bh >> 4;
  const int h = bh & 15;

  __shared__ __align__(16) float q_lds[HD_];
  __shared__ int ck[160];
  __shared__ float cv[160];

  q_lds[lane] = qw[((size_t)bh * N_ + qi) * HD_ + lane];
  __syncthreads();

  // scores: lane handles keys lane+64j, j=0..15
  const float* kb = kw + ((size_t)bh << 16);
  float s[16];
#pragma unroll
  for (int j = 0; j < 16; ++j) {
    const int key = lane + (j << 6);
    const float4* kr = (const float4*)(kb + ((size_t)key << 6));
    float acc = 0.f;
#pragma unroll
    for (int dd = 0; dd < 16; ++dd) {
      const float4 kv = kr[dd];
      const float4 qv = *(const float4*)(q_lds + dd * 4);
      acc = fmaf(kv.x, qv.x, acc);
      acc = fmaf(kv.y, qv.y, acc);
      acc = fmaf(kv.z, qv.z, acc);
      acc = fmaf(kv.w, qv.w, acc);
    }
    s[j] = (acc * 0.125f) / 0.8f;  // *SCALE then /TEMPERATURE, as reference
  }

  // row max
  float m = s[0];
#pragma unroll
  for (int j = 1; j < 16; ++j) m = fmaxf(m, s[j]);
  m = wmaxf(m);

  unsigned u[16];
#pragma unroll
  for (int j = 0; j < 16; ++j) u[j] = orderu(s[j]);

  // top-k: kth = largest t with count(u >= t) >= 64  == sorted_desc[63]
  unsigned lo = 0u, hi = 0xFFFFFFFFu;
  while (lo < hi) {
    const unsigned mid = lo + ((hi - lo) >> 1) + 1u;
    int c = 0;
#pragma unroll
    for (int j = 0; j < 16; ++j) c += (u[j] >= mid) ? 1 : 0;
    c = wsumi(c);
    if (c >= 64) lo = mid; else hi = mid - 1u;
  }
  const unsigned kthu = lo;

  // exp over kept set (others contribute exactly 0, matching exp(-1e9-m) underflow)
  float e[16];
#pragma unroll
  for (int j = 0; j < 16; ++j)
    e[j] = (u[j] >= kthu) ? expf(s[j] - m) : 0.f;
  float Z = 0.f;
#pragma unroll
  for (int j = 0; j < 16; ++j) Z += e[j];
  Z = wsumf(Z);
  const float limit = 0.9f * Z;  // TOP_P * Z

  // top-p: value v kept iff sum_{s>v} e <= 0.9*Z (exclusive-cumsum at first
  // occurrence; exact under ties). Find t* = min t with h(t) <= limit.
  unsigned nlo = 0u, nhi = 0xFFFFFFFFu;  // h(0)=Z>limit, h(max)=0<=limit
  while (nhi - nlo > 1u) {
    const unsigned mid = nlo + ((nhi - nlo) >> 1);
    float hs = 0.f;
#pragma unroll
    for (int j = 0; j < 16; ++j) hs += (u[j] > mid) ? e[j] : 0.f;
    hs = wsumf(hs);
    if (hs <= limit) nhi = mid; else nlo = mid;
  }
  const unsigned tstar = nhi;  // final keep: u >= tstar (tstar >= kthu provable)

  float Z2 = 0.f;
#pragma unroll
  for (int j = 0; j < 16; ++j) Z2 += (u[j] >= tstar) ? e[j] : 0.f;
  Z2 = wsumf(Z2);

  const float wsc = fac[(b << 10) + qi] / Z2;  // (1+lc*theta)/Z2

  // ballot-compact surviving keys (ascending key order preserved)
  int Mtot = 0;
#pragma unroll
  for (int j = 0; j < 16; ++j) {
    const bool f = (u[j] >= tstar) && (u[j] >= kthu);
    const unsigned long long mb = __ballot(f);
    if (f) {
      const int pos = Mtot + (int)__popcll(mb & ((1ull << lane) - 1ull));
      if (pos < 160) {
        ck[pos] = lane + (j << 6);
        cv[pos] = e[j] * wsc;
      }
    }
    Mtot += (int)__popcll(mb);
  }
  if (Mtot > 160) Mtot = 160;
  __syncthreads();

  // PV over ~64 surviving keys; lane = output dim d
  const float* vb = vw + ((size_t)bh << 16);
  float a0 = 0.f, a1 = 0.f, a2 = 0.f, a3 = 0.f;
  int i = 0;
  for (; i + 4 <= Mtot; i += 4) {
    const int k0 = ck[i], k1 = ck[i + 1], k2 = ck[i + 2], k3 = ck[i + 3];
    const float c0 = cv[i], c1 = cv[i + 1], c2 = cv[i + 2], c3 = cv[i + 3];
    a0 = fmaf(c0, vb[((size_t)k0 << 6) + lane], a0);
    a1 = fmaf(c1, vb[((size_t)k1 << 6) + lane], a1);
    a2 = fmaf(c2, vb[((size_t)k2 << 6) + lane], a2);
    a3 = fmaf(c3, vb[((size_t)k3 << 6) + lane], a3);
  }
  for (; i < Mtot; ++i)
    a0 = fmaf(cv[i], vb[((size_t)ck[i] << 6) + lane], a0);
  const float o = (a0 + a1) + (a2 + a3);

  // write concat-head layout (B,N,C) for the output projection
  ao[(((size_t)b << 10) + qi) * C_ + (h << 6) + lane] = o;
}

extern "C" void kernel_launch(void* const* d_in, const int* in_sizes, int n_in,
                              void* d_out, int out_size, void* d_ws,
                              size_t ws_size, hipStream_t stream) {
  const float* x = (const float*)d_in[0];
  const float* wqkv = (const float*)d_in[1];
  const float* wout = (const float*)d_in[2];
  const float* bout = (const float*)d_in[3];
  const float* alpha = (const float*)d_in[4];
  const float* beta = (const float*)d_in[5];
  float* out = (float*)d_out;

  float* ws = (float*)d_ws;
  const size_t SZ = (size_t)B_ * H_ * N_ * HD_;  // 2M floats
  float* qw = ws;
  float* kw = ws + SZ;
  float* vw = ws + 2 * SZ;
  float* ao = ws + 3 * SZ;
  float* fc = ws + 4 * SZ;

  factor_kernel<<<B_ * N_, 64, 0, stream>>>(x, alpha, beta, fc);
  gemm_qkv_kernel<<<dim3(3 * C_ / 128, B_ * N_ / 128), 256, 0, stream>>>(
      x, wqkv, qw, kw, vw);
  attn_kernel<<<B_ * H_ * N_, 64, 0, stream>>>(qw, kw, vw, fc, ao);
  gemm_out_kernel<<<dim3(C_ / 128, B_ * N_ / 128), 256, 0, stream>>>(
      ao, wout, bout, out);
}

// Round 2
// 2401.227 us; speedup vs baseline: 1.0032x; 1.0032x over previous
//
#include <hip/hip_runtime.h>

#define B_ 2
#define N_ 1024
#define C_ 1024
#define H_ 16
#define HD_ 64

// ---------- wave-wide (64-lane) helpers ----------
__device__ __forceinline__ float wsumf(float x) {
#pragma unroll
  for (int off = 32; off; off >>= 1) x += __shfl_xor(x, off, 64);
  return x;
}
__device__ __forceinline__ float wmaxf(float x) {
#pragma unroll
  for (int off = 32; off; off >>= 1) x = fmaxf(x, __shfl_xor(x, off, 64));
  return x;
}
// order-preserving float->uint map (total order matches float compare for non-NaN)
__device__ __forceinline__ unsigned orderu(float f) {
  unsigned b = __float_as_uint(f);
  return (b & 0x80000000u) ? ~b : (b | 0x80000000u);
}

// ---------- NKAT per-token factor ----------
__global__ __launch_bounds__(64) void factor_kernel(
    const float* __restrict__ x, const float* __restrict__ alpha_p,
    const float* __restrict__ beta_p, float* __restrict__ fac) {
  const int row = blockIdx.x;  // b*N + n
  const int lane = threadIdx.x;
  const float4* xr = (const float4*)(x + (size_t)row * C_);
  float s = 0.f, ss = 0.f;
#pragma unroll
  for (int j = 0; j < 4; ++j) {
    float4 v = xr[lane + 64 * j];
    s += v.x + v.y + v.z + v.w;
    ss += v.x * v.x + v.y * v.y + v.z * v.z + v.w * v.w;
  }
  s = wsumf(s);
  ss = wsumf(ss);
  const float mean = s * (1.f / 1024.f);
  const float var = ss * (1.f / 1024.f) - mean * mean;
  const float theta =
      alpha_p[0] * tanhf(mean) + beta_p[0] * (1.f / (1.f + __expf(-var)));
  if (lane == 0) fac[row] = 1.f + 0.45125f * theta;  // lc = 0.5*0.95^2
}

// ---------- shared f32 GEMM core: 128x128 tile, 256 thr, 8x8/thread, BK=8 ----------
__device__ __forceinline__ void gemm_core(const float* __restrict__ A,
                                          const float* __restrict__ Bm, int K,
                                          int N, int m0, int n0,
                                          float* __restrict__ a_lds,
                                          float* __restrict__ b_lds,
                                          float acc[8][8]) {
  const int tid = threadIdx.x;
  const int tx = tid & 15, ty = tid >> 4;
  const int r = tid >> 1, c4 = (tid & 1) << 2;     // A tile: 128 rows x 8 cols
  const int rb = tid >> 5, cb = (tid & 31) << 2;   // B tile: 8 rows x 128 cols
  for (int k0 = 0; k0 < K; k0 += 8) {
    const float4 av = *(const float4*)(A + (size_t)(m0 + r) * K + k0 + c4);
    const float4 bv = *(const float4*)(Bm + (size_t)(k0 + rb) * N + n0 + cb);
    __syncthreads();  // previous iteration's LDS reads done
    a_lds[(c4 + 0) * 128 + r] = av.x;  // store A transposed: [k][m]
    a_lds[(c4 + 1) * 128 + r] = av.y;
    a_lds[(c4 + 2) * 128 + r] = av.z;
    a_lds[(c4 + 3) * 128 + r] = av.w;
    *(float4*)(b_lds + rb * 128 + cb) = bv;
    __syncthreads();
#pragma unroll
    for (int kk = 0; kk < 8; ++kk) {
      const float4 a0 = *(const float4*)(a_lds + kk * 128 + ty * 8);
      const float4 a1 = *(const float4*)(a_lds + kk * 128 + ty * 8 + 4);
      const float4 b0 = *(const float4*)(b_lds + kk * 128 + tx * 8);
      const float4 b1 = *(const float4*)(b_lds + kk * 128 + tx * 8 + 4);
      const float af[8] = {a0.x, a0.y, a0.z, a0.w, a1.x, a1.y, a1.z, a1.w};
      const float bf[8] = {b0.x, b0.y, b0.z, b0.w, b1.x, b1.y, b1.z, b1.w};
#pragma unroll
      for (int i = 0; i < 8; ++i)
#pragma unroll
        for (int jj = 0; jj < 8; ++jj)
          acc[i][jj] = fmaf(af[i], bf[jj], acc[i][jj]);
    }
  }
}

// ---------- qkv = x @ w_qkv, scatter into q/k/v in (B,H,N,HD) layout ----------
__global__ __launch_bounds__(256) void gemm_qkv_kernel(
    const float* __restrict__ x, const float* __restrict__ w,
    float* __restrict__ q, float* __restrict__ k, float* __restrict__ v) {
  __shared__ __align__(16) float a_lds[8 * 128];
  __shared__ __align__(16) float b_lds[8 * 128];
  float acc[8][8];
#pragma unroll
  for (int i = 0; i < 8; ++i)
#pragma unroll
    for (int jj = 0; jj < 8; ++jj) acc[i][jj] = 0.f;
  const int m0 = blockIdx.y * 128, n0 = blockIdx.x * 128;
  gemm_core(x, w, C_, 3 * C_, m0, n0, a_lds, b_lds, acc);

  const int tx = threadIdx.x & 15, ty = threadIdx.x >> 4;
  const int j0 = n0 + tx * 8;           // 8 consecutive cols: same sel, same head
  const int sel = j0 >> 10;             // 0=q 1=k 2=v
  const int hh = (j0 >> 6) & 15;
  const int d0 = j0 & 63;
  float* dstbuf = sel == 0 ? q : (sel == 1 ? k : v);
#pragma unroll
  for (int i = 0; i < 8; ++i) {
    const int mm = m0 + ty * 8 + i;
    const int bb = mm >> 10, nn = mm & 1023;
    float* dst = dstbuf + ((((size_t)bb << 4) + hh) * N_ + nn) * HD_ + d0;
    *(float4*)dst = make_float4(acc[i][0], acc[i][1], acc[i][2], acc[i][3]);
    *(float4*)(dst + 4) = make_float4(acc[i][4], acc[i][5], acc[i][6], acc[i][7]);
  }
}

// ---------- out = attn_out @ w_out + b_out ----------
__global__ __launch_bounds__(256) void gemm_out_kernel(
    const float* __restrict__ a, const float* __restrict__ w,
    const float* __restrict__ bias, float* __restrict__ out) {
  __shared__ __align__(16) float a_lds[8 * 128];
  __shared__ __align__(16) float b_lds[8 * 128];
  float acc[8][8];
#pragma unroll
  for (int i = 0; i < 8; ++i)
#pragma unroll
    for (int jj = 0; jj < 8; ++jj) acc[i][jj] = 0.f;
  const int m0 = blockIdx.y * 128, n0 = blockIdx.x * 128;
  gemm_core(a, w, C_, C_, m0, n0, a_lds, b_lds, acc);

  const int tx = threadIdx.x & 15, ty = threadIdx.x >> 4;
  const int j0 = n0 + tx * 8;
  const float4 bs0 = *(const float4*)(bias + j0);
  const float4 bs1 = *(const float4*)(bias + j0 + 4);
#pragma unroll
  for (int i = 0; i < 8; ++i) {
    const int mm = m0 + ty * 8 + i;
    float* dst = out + (size_t)mm * C_ + j0;
    *(float4*)dst = make_float4(acc[i][0] + bs0.x, acc[i][1] + bs0.y,
                                acc[i][2] + bs0.z, acc[i][3] + bs0.w);
    *(float4*)(dst + 4) = make_float4(acc[i][4] + bs1.x, acc[i][5] + bs1.y,
                                      acc[i][6] + bs1.z, acc[i][7] + bs1.w);
  }
}

// ---------- per-row attention, 4 queries/block (1 wave each) ----------
// top-k: ballot-count binary search (no shuffles)
// top-p: compact 64 survivors 1/lane -> bitonic sort -> prefix sum -> threshold
__global__ __launch_bounds__(256, 4) void attn_kernel(
    const float* __restrict__ qw, const float* __restrict__ kw,
    const float* __restrict__ vw, const float* __restrict__ fac,
    float* __restrict__ ao) {
  const int lane = threadIdx.x & 63;
  const int wid = threadIdx.x >> 6;
  const int row = blockIdx.x * 4 + wid;  // bh*N + q
  const int qi = row & (N_ - 1);
  const int bh = row >> 10;
  const int b = bh >> 4;
  const int h = bh & 15;

  __shared__ __align__(16) float q_lds[4][HD_];
  __shared__ unsigned su[4][64];
  __shared__ float sv[4][64];
  __shared__ int ck[4][96];
  __shared__ float cv[4][96];

  q_lds[wid][lane] = qw[((size_t)bh * N_ + qi) * HD_ + lane];
  __syncthreads();

  // scores: lane handles keys lane+64j, j=0..15
  const float* kb = kw + ((size_t)bh << 16);
  float s[16];
#pragma unroll
  for (int j = 0; j < 16; ++j) {
    const int key = lane + (j << 6);
    const float4* kr = (const float4*)(kb + ((size_t)key << 6));
    float acc = 0.f;
#pragma unroll
    for (int dd = 0; dd < 16; ++dd) {
      const float4 kv = kr[dd];
      const float4 qv = *(const float4*)(&q_lds[wid][dd * 4]);
      acc = fmaf(kv.x, qv.x, acc);
      acc = fmaf(kv.y, qv.y, acc);
      acc = fmaf(kv.z, qv.z, acc);
      acc = fmaf(kv.w, qv.w, acc);
    }
    s[j] = (acc * 0.125f) / 0.8f;  // *SCALE then /TEMPERATURE
  }

  // row max
  float m = s[0];
#pragma unroll
  for (int j = 1; j < 16; ++j) m = fmaxf(m, s[j]);
  m = wmaxf(m);

  unsigned u[16];
#pragma unroll
  for (int j = 0; j < 16; ++j) u[j] = orderu(s[j]);

  const unsigned long long ltmask = (1ull << lane) - 1ull;

  // top-k: kth = largest t with count(u >= t) >= 64 (ballot+popcount, no shfl)
  unsigned lo = 0u, hi = orderu(m);
  while (lo < hi) {
    const unsigned mid = lo + ((hi - lo) >> 1) + 1u;
    int c = 0;
#pragma unroll
    for (int j = 0; j < 16; ++j)
      c += (int)__popcll(__ballot(u[j] >= mid));
    if (c >= 64) lo = mid; else hi = mid - 1u;
  }
  const unsigned kthu = lo;

  // exp over kept set (others are exactly 0, matching exp(NEG-m) underflow)
  float e[16];
#pragma unroll
  for (int j = 0; j < 16; ++j) e[j] = (u[j] >= kthu) ? expf(s[j] - m) : 0.f;
  float Z = 0.f;
#pragma unroll
  for (int j = 0; j < 16; ++j) Z += e[j];
  Z = wsumf(Z);
  const float limit = 0.9f * Z;  // TOP_P * Z

  // compact survivors (u>=kth) one per lane via ballot prefix
  int base = 0;
#pragma unroll
  for (int j = 0; j < 16; ++j) {
    const bool f = (u[j] >= kthu);
    const unsigned long long mb = __ballot(f);
    if (f) {
      const int pos = base + (int)__popcll(mb & ltmask);
      if (pos < 64) {
        su[wid][pos] = u[j];
        sv[wid][pos] = e[j];
      }
    }
    base += (int)__popcll(mb);
  }
  __syncthreads();
  const int nsurv = base > 64 ? 64 : base;  // == 64 generically

  // per-lane survivor; empties sort to the end (key ascending = u descending)
  unsigned sk = (lane < nsurv) ? ~su[wid][lane] : 0xFFFFFFFFu;
  float se = (lane < nsurv) ? sv[wid][lane] : 0.f;

  // bitonic sort across 64 lanes, ascending by sk (= descending by u)
#pragma unroll
  for (int k = 2; k <= 64; k <<= 1) {
#pragma unroll
    for (int j = k >> 1; j; j >>= 1) {
      const unsigned pk = (unsigned)__shfl_xor((int)sk, j, 64);
      const float pe = __shfl_xor(se, j, 64);
      const bool takeMin = (((lane & j) == 0) == ((lane & k) == 0));
      const bool sw = takeMin ? (pk < sk) : (pk > sk);
      if (sw) { sk = pk; se = pe; }
    }
  }

  // inclusive prefix sum of e in sorted (descending-u) order
  float pre = se;
#pragma unroll
  for (int off = 1; off <= 32; off <<= 1) {
    const float t = __shfl_up(pre, off, 64);
    if (lane >= off) pre += t;
  }
  const float excl = pre - se;
  const bool keep = (excl <= limit);  // first lane always kept (excl==0)
  const unsigned long long km = __ballot(keep);
  const int L = 63 - __builtin_clzll(km);           // last kept sorted position
  const unsigned thr = ~(unsigned)__shfl((int)sk, L, 64);  // = min kept value

  // Z over final kept set (u >= thr), exact under ties
  float z2l = 0.f;
#pragma unroll
  for (int j = 0; j < 16; ++j) z2l += (u[j] >= thr) ? e[j] : 0.f;
  const float Z2 = wsumf(z2l);

  const float wsc = fac[(b << 10) + qi] / Z2;  // (1+lc*theta)/Z

  // compact final kept (idx, weight) for PV
  int M = 0;
#pragma unroll
  for (int j = 0; j < 16; ++j) {
    const bool f = (u[j] >= thr);
    const unsigned long long mb = __ballot(f);
    if (f) {
      const int pos = M + (int)__popcll(mb & ltmask);
      if (pos < 96) {
        ck[wid][pos] = lane + (j << 6);
        cv[wid][pos] = e[j] * wsc;
      }
    }
    M += (int)__popcll(mb);
  }
  if (M > 96) M = 96;
  __syncthreads();

  // PV over ~64 surviving keys; lane = output dim d
  const float* vb = vw + ((size_t)bh << 16);
  float a0 = 0.f, a1 = 0.f, a2 = 0.f, a3 = 0.f;
  int i = 0;
  for (; i + 4 <= M; i += 4) {
    const int k0 = ck[wid][i], k1 = ck[wid][i + 1];
    const int k2 = ck[wid][i + 2], k3 = ck[wid][i + 3];
    const float c0 = cv[wid][i], c1 = cv[wid][i + 1];
    const float c2 = cv[wid][i + 2], c3 = cv[wid][i + 3];
    a0 = fmaf(c0, vb[((size_t)k0 << 6) + lane], a0);
    a1 = fmaf(c1, vb[((size_t)k1 << 6) + lane], a1);
    a2 = fmaf(c2, vb[((size_t)k2 << 6) + lane], a2);
    a3 = fmaf(c3, vb[((size_t)k3 << 6) + lane], a3);
  }
  for (; i < M; ++i)
    a0 = fmaf(cv[wid][i], vb[((size_t)ck[wid][i] << 6) + lane], a0);
  const float o = (a0 + a1) + (a2 + a3);

  // concat-head layout (B,N,C) for the output projection
  ao[(((size_t)b << 10) + qi) * C_ + (h << 6) + lane] = o;
}

extern "C" void kernel_launch(void* const* d_in, const int* in_sizes, int n_in,
                              void* d_out, int out_size, void* d_ws,
                              size_t ws_size, hipStream_t stream) {
  const float* x = (const float*)d_in[0];
  const float* wqkv = (const float*)d_in[1];
  const float* wout = (const float*)d_in[2];
  const float* bout = (const float*)d_in[3];
  const float* alpha = (const float*)d_in[4];
  const float* beta = (const float*)d_in[5];
  float* out = (float*)d_out;

  float* ws = (float*)d_ws;
  const size_t SZ = (size_t)B_ * H_ * N_ * HD_;  // 2M floats
  float* qw = ws;
  float* kw = ws + SZ;
  float* vw = ws + 2 * SZ;
  float* ao = ws + 3 * SZ;
  float* fc = ws + 4 * SZ;

  factor_kernel<<<B_ * N_, 64, 0, stream>>>(x, alpha, beta, fc);
  gemm_qkv_kernel<<<dim3(3 * C_ / 128, B_ * N_ / 128), 256, 0, stream>>>(
      x, wqkv, qw, kw, vw);
  attn_kernel<<<(B_ * H_ * N_) / 4, 256, 0, stream>>>(qw, kw, vw, fc, ao);
  gemm_out_kernel<<<dim3(C_ / 128, B_ * N_ / 128), 256, 0, stream>>>(
      ao, wout, bout, out);
}

// Round 3
// 734.451 us; speedup vs baseline: 3.2798x; 3.2694x over previous
//
#include <hip/hip_runtime.h>

#define B_ 2
#define N_ 1024
#define C_ 1024
#define H_ 16
#define HD_ 64

// ---------- wave-wide (64-lane) helpers ----------
__device__ __forceinline__ float wsumf(float x) {
#pragma unroll
  for (int off = 32; off; off >>= 1) x += __shfl_xor(x, off, 64);
  return x;
}
// order-preserving float->uint map (total order matches float compare for non-NaN)
__device__ __forceinline__ unsigned orderu(float f) {
  unsigned b = __float_as_uint(f);
  return (b & 0x80000000u) ? ~b : (b | 0x80000000u);
}
__device__ __forceinline__ float iorderu(unsigned x) {
  unsigned b = (x & 0x80000000u) ? (x & 0x7FFFFFFFu) : ~x;
  return __uint_as_float(b);
}

// ---------- NKAT per-token factor ----------
__global__ __launch_bounds__(64) void factor_kernel(
    const float* __restrict__ x, const float* __restrict__ alpha_p,
    const float* __restrict__ beta_p, float* __restrict__ fac) {
  const int row = blockIdx.x;  // b*N + n
  const int lane = threadIdx.x;
  const float4* xr = (const float4*)(x + (size_t)row * C_);
  float s = 0.f, ss = 0.f;
#pragma unroll
  for (int j = 0; j < 4; ++j) {
    float4 v = xr[lane + 64 * j];
    s += v.x + v.y + v.z + v.w;
    ss += v.x * v.x + v.y * v.y + v.z * v.z + v.w * v.w;
  }
  s = wsumf(s);
  ss = wsumf(ss);
  const float mean = s * (1.f / 1024.f);
  const float var = ss * (1.f / 1024.f) - mean * mean;
  const float theta =
      alpha_p[0] * tanhf(mean) + beta_p[0] * (1.f / (1.f + __expf(-var)));
  if (lane == 0) fac[row] = 1.f + 0.45125f * theta;  // lc = 0.5*0.95^2
}

// ---------- shared f32 GEMM core: 128x128 tile, 256 thr, 8x8/thread, BK=8 ----------
__device__ __forceinline__ void gemm_core(const float* __restrict__ A,
                                          const float* __restrict__ Bm, int K,
                                          int N, int m0, int n0,
                                          float* __restrict__ a_lds,
                                          float* __restrict__ b_lds,
                                          float acc[8][8]) {
  const int tid = threadIdx.x;
  const int tx = tid & 15, ty = tid >> 4;
  const int r = tid >> 1, c4 = (tid & 1) << 2;     // A tile: 128 rows x 8 cols
  const int rb = tid >> 5, cb = (tid & 31) << 2;   // B tile: 8 rows x 128 cols
  for (int k0 = 0; k0 < K; k0 += 8) {
    const float4 av = *(const float4*)(A + (size_t)(m0 + r) * K + k0 + c4);
    const float4 bv = *(const float4*)(Bm + (size_t)(k0 + rb) * N + n0 + cb);
    __syncthreads();  // previous iteration's LDS reads done
    a_lds[(c4 + 0) * 128 + r] = av.x;  // store A transposed: [k][m]
    a_lds[(c4 + 1) * 128 + r] = av.y;
    a_lds[(c4 + 2) * 128 + r] = av.z;
    a_lds[(c4 + 3) * 128 + r] = av.w;
    *(float4*)(b_lds + rb * 128 + cb) = bv;
    __syncthreads();
#pragma unroll
    for (int kk = 0; kk < 8; ++kk) {
      const float4 a0 = *(const float4*)(a_lds + kk * 128 + ty * 8);
      const float4 a1 = *(const float4*)(a_lds + kk * 128 + ty * 8 + 4);
      const float4 b0 = *(const float4*)(b_lds + kk * 128 + tx * 8);
      const float4 b1 = *(const float4*)(b_lds + kk * 128 + tx * 8 + 4);
      const float af[8] = {a0.x, a0.y, a0.z, a0.w, a1.x, a1.y, a1.z, a1.w};
      const float bf[8] = {b0.x, b0.y, b0.z, b0.w, b1.x, b1.y, b1.z, b1.w};
#pragma unroll
      for (int i = 0; i < 8; ++i)
#pragma unroll
        for (int jj = 0; jj < 8; ++jj)
          acc[i][jj] = fmaf(af[i], bf[jj], acc[i][jj]);
    }
  }
}

// ---------- qkv = x @ w_qkv, scatter into q/k/v in (B,H,N,HD) layout ----------
__global__ __launch_bounds__(256) void gemm_qkv_kernel(
    const float* __restrict__ x, const float* __restrict__ w,
    float* __restrict__ q, float* __restrict__ k, float* __restrict__ v) {
  __shared__ __align__(16) float a_lds[8 * 128];
  __shared__ __align__(16) float b_lds[8 * 128];
  float acc[8][8];
#pragma unroll
  for (int i = 0; i < 8; ++i)
#pragma unroll
    for (int jj = 0; jj < 8; ++jj) acc[i][jj] = 0.f;
  const int m0 = blockIdx.y * 128, n0 = blockIdx.x * 128;
  gemm_core(x, w, C_, 3 * C_, m0, n0, a_lds, b_lds, acc);

  const int tx = threadIdx.x & 15, ty = threadIdx.x >> 4;
  const int j0 = n0 + tx * 8;           // 8 consecutive cols: same sel, same head
  const int sel = j0 >> 10;             // 0=q 1=k 2=v
  const int hh = (j0 >> 6) & 15;
  const int d0 = j0 & 63;
  float* dstbuf = sel == 0 ? q : (sel == 1 ? k : v);
#pragma unroll
  for (int i = 0; i < 8; ++i) {
    const int mm = m0 + ty * 8 + i;
    const int bb = mm >> 10, nn = mm & 1023;
    float* dst = dstbuf + ((((size_t)bb << 4) + hh) * N_ + nn) * HD_ + d0;
    *(float4*)dst = make_float4(acc[i][0], acc[i][1], acc[i][2], acc[i][3]);
    *(float4*)(dst + 4) = make_float4(acc[i][4], acc[i][5], acc[i][6], acc[i][7]);
  }
}

// ---------- out = attn_out @ w_out + b_out ----------
__global__ __launch_bounds__(256) void gemm_out_kernel(
    const float* __restrict__ a, const float* __restrict__ w,
    const float* __restrict__ bias, float* __restrict__ out) {
  __shared__ __align__(16) float a_lds[8 * 128];
  __shared__ __align__(16) float b_lds[8 * 128];
  float acc[8][8];
#pragma unroll
  for (int i = 0; i < 8; ++i)
#pragma unroll
    for (int jj = 0; jj < 8; ++jj) acc[i][jj] = 0.f;
  const int m0 = blockIdx.y * 128, n0 = blockIdx.x * 128;
  gemm_core(a, w, C_, C_, m0, n0, a_lds, b_lds, acc);

  const int tx = threadIdx.x & 15, ty = threadIdx.x >> 4;
  const int j0 = n0 + tx * 8;
  const float4 bs0 = *(const float4*)(bias + j0);
  const float4 bs1 = *(const float4*)(bias + j0 + 4);
#pragma unroll
  for (int i = 0; i < 8; ++i) {
    const int mm = m0 + ty * 8 + i;
    float* dst = out + (size_t)mm * C_ + j0;
    *(float4*)dst = make_float4(acc[i][0] + bs0.x, acc[i][1] + bs0.y,
                                acc[i][2] + bs0.z, acc[i][3] + bs0.w);
    *(float4*)(dst + 4) = make_float4(acc[i][4] + bs1.x, acc[i][5] + bs1.y,
                                      acc[i][6] + bs1.z, acc[i][7] + bs1.w);
  }
}

// ---------- attention: 4 waves/block, 4 queries/wave (shared K streaming) ----------
// scores: lane handles keys lane+64j for 4 queries at once (K row read once)
// top-k: ballot-count binary search; top-p: bitonic sort + prefix scan
__global__ __launch_bounds__(256) void attn_kernel(
    const float* __restrict__ qw, const float* __restrict__ kw,
    const float* __restrict__ vw, const float* __restrict__ fac,
    float* __restrict__ ao) {
  const int lane = threadIdx.x & 63;
  const int wid = threadIdx.x >> 6;
  const int qblk = blockIdx.x * 16;      // 16 queries per block, same (b,h)
  const int bh = qblk >> 10;
  const int b = bh >> 4, h = bh & 15;
  const int q0 = (qblk & (N_ - 1)) + wid * 4;  // first query of this wave

  __shared__ __align__(16) float q_lds[4][4][HD_];
  __shared__ unsigned su[4][64];
  __shared__ float sv[4][64];
  __shared__ int ck[4][96];
  __shared__ float cv[4][96];

  // load this wave's 4 query vectors (each lane: one float4)
  {
    const int qq = lane >> 4, dp = (lane & 15) << 2;
    *(float4*)(&q_lds[wid][qq][dp]) =
        *(const float4*)(qw + ((size_t)bh * N_ + q0 + qq) * HD_ + dp);
  }
  __syncthreads();

  const float* kb = kw + ((size_t)bh << 16);
  const unsigned long long ltmask = (1ull << lane) - 1ull;
  unsigned u[4][16];  // [query][j], persistent selection state

  // ---- score phase: j-tiled so K rows stream through L1, q from LDS ----
  for (int jt = 0; jt < 4; ++jt) {
    float acc[4][4];  // [jl][query]
#pragma unroll
    for (int a = 0; a < 4; ++a)
#pragma unroll
      for (int c = 0; c < 4; ++c) acc[a][c] = 0.f;
#pragma unroll 2
    for (int dd2 = 0; dd2 < 16; ++dd2) {
      float4 qv[4];
#pragma unroll
      for (int q = 0; q < 4; ++q)
        qv[q] = *(const float4*)(&q_lds[wid][q][dd2 << 2]);
#pragma unroll
      for (int jl = 0; jl < 4; ++jl) {
        const int key = lane + (((jt << 2) + jl) << 6);
        const float4 kv =
            *(const float4*)(kb + ((size_t)key << 6) + (dd2 << 2));
#pragma unroll
        for (int q = 0; q < 4; ++q) {
          acc[jl][q] = fmaf(kv.x, qv[q].x, acc[jl][q]);
          acc[jl][q] = fmaf(kv.y, qv[q].y, acc[jl][q]);
          acc[jl][q] = fmaf(kv.z, qv[q].z, acc[jl][q]);
          acc[jl][q] = fmaf(kv.w, qv[q].w, acc[jl][q]);
        }
      }
    }
#pragma unroll
    for (int jl = 0; jl < 4; ++jl)
#pragma unroll
      for (int q = 0; q < 4; ++q)
        u[q][(jt << 2) + jl] = orderu((acc[jl][q] * 0.125f) / 0.8f);
  }

  // ---- selection + PV, one query at a time ----
  const float* vb = vw + ((size_t)bh << 16);
#pragma unroll
  for (int qq = 0; qq < 4; ++qq) {
    // wave max (integer max == float max under orderu)
    unsigned mu = u[qq][0];
#pragma unroll
    for (int j = 1; j < 16; ++j) mu = max(mu, u[qq][j]);
#pragma unroll
    for (int off = 32; off; off >>= 1)
      mu = max(mu, (unsigned)__shfl_xor((int)mu, off, 64));
    const float m = iorderu(mu);

    // top-k: kth = largest t with count(u >= t) >= 64 (ballot+popcount)
    unsigned lo = 0u, hi = mu;
    while (lo < hi) {
      const unsigned mid = lo + ((hi - lo) >> 1) + 1u;
      int c = 0;
#pragma unroll
      for (int j = 0; j < 16; ++j)
        c += (int)__popcll(__ballot(u[qq][j] >= mid));
      if (c >= 64) lo = mid; else hi = mid - 1u;
    }
    const unsigned kthu = lo;

    // exp over kept set (others exactly 0 = exp(NEG-m) underflow)
    float e[16];
    float zl = 0.f;
#pragma unroll
    for (int j = 0; j < 16; ++j) {
      const float ej =
          (u[qq][j] >= kthu) ? expf(iorderu(u[qq][j]) - m) : 0.f;
      e[j] = ej;
      zl += ej;
    }
    const float Z = wsumf(zl);
    const float limit = 0.9f * Z;  // TOP_P * Z

    // compact survivors (u>=kth) one per lane
    int base = 0;
#pragma unroll
    for (int j = 0; j < 16; ++j) {
      const bool f = (u[qq][j] >= kthu);
      const unsigned long long mb = __ballot(f);
      if (f) {
        const int pos = base + (int)__popcll(mb & ltmask);
        if (pos < 64) {
          su[wid][pos] = u[qq][j];
          sv[wid][pos] = e[j];
        }
      }
      base += (int)__popcll(mb);
    }
    __syncthreads();
    const int nsurv = base > 64 ? 64 : base;

    // bitonic sort across 64 lanes, ascending by ~u (= descending by u)
    unsigned sk = (lane < nsurv) ? ~su[wid][lane] : 0xFFFFFFFFu;
    float se = (lane < nsurv) ? sv[wid][lane] : 0.f;
#pragma unroll
    for (int k = 2; k <= 64; k <<= 1) {
#pragma unroll
      for (int j = k >> 1; j; j >>= 1) {
        const unsigned pk = (unsigned)__shfl_xor((int)sk, j, 64);
        const float pe = __shfl_xor(se, j, 64);
        const bool takeMin = (((lane & j) == 0) == ((lane & k) == 0));
        const bool sw = takeMin ? (pk < sk) : (pk > sk);
        if (sw) { sk = pk; se = pe; }
      }
    }

    // inclusive prefix sum of e in sorted (descending-u) order
    float pre = se;
#pragma unroll
    for (int off = 1; off <= 32; off <<= 1) {
      const float t = __shfl_up(pre, off, 64);
      if (lane >= off) pre += t;
    }
    const float excl = pre - se;
    const bool keep = (excl <= limit);  // first always kept (excl==0)
    const unsigned long long km = __ballot(keep);
    const int L = 63 - __builtin_clzll(km);
    const unsigned thr = ~(unsigned)__shfl((int)sk, L, 64);  // min kept value

    // Z over final kept set (u >= thr)
    float z2l = 0.f;
#pragma unroll
    for (int j = 0; j < 16; ++j) z2l += (u[qq][j] >= thr) ? e[j] : 0.f;
    const float Z2 = wsumf(z2l);
    const float wsc = fac[(b << 10) + q0 + qq] / Z2;

    // compact final kept (idx, weight) for PV
    int M = 0;
#pragma unroll
    for (int j = 0; j < 16; ++j) {
      const bool f = (u[qq][j] >= thr);
      const unsigned long long mb = __ballot(f);
      if (f) {
        const int pos = M + (int)__popcll(mb & ltmask);
        if (pos < 96) {
          ck[wid][pos] = lane + (j << 6);
          cv[wid][pos] = e[j] * wsc;
        }
      }
      M += (int)__popcll(mb);
    }
    if (M > 96) M = 96;
    __syncthreads();

    // PV over surviving keys; lane = output dim d
    float a0 = 0.f, a1 = 0.f, a2 = 0.f, a3 = 0.f;
    int i = 0;
    for (; i + 4 <= M; i += 4) {
      const int k0 = ck[wid][i], k1 = ck[wid][i + 1];
      const int k2 = ck[wid][i + 2], k3 = ck[wid][i + 3];
      const float c0 = cv[wid][i], c1 = cv[wid][i + 1];
      const float c2 = cv[wid][i + 2], c3 = cv[wid][i + 3];
      a0 = fmaf(c0, vb[((size_t)k0 << 6) + lane], a0);
      a1 = fmaf(c1, vb[((size_t)k1 << 6) + lane], a1);
      a2 = fmaf(c2, vb[((size_t)k2 << 6) + lane], a2);
      a3 = fmaf(c3, vb[((size_t)k3 << 6) + lane], a3);
    }
    for (; i < M; ++i)
      a0 = fmaf(cv[wid][i], vb[((size_t)ck[wid][i] << 6) + lane], a0);
    const float o = (a0 + a1) + (a2 + a3);

    ao[(((size_t)b << 10) + q0 + qq) * C_ + (h << 6) + lane] = o;
  }
}

extern "C" void kernel_launch(void* const* d_in, const int* in_sizes, int n_in,
                              void* d_out, int out_size, void* d_ws,
                              size_t ws_size, hipStream_t stream) {
  const float* x = (const float*)d_in[0];
  const float* wqkv = (const float*)d_in[1];
  const float* wout = (const float*)d_in[2];
  const float* bout = (const float*)d_in[3];
  const float* alpha = (const float*)d_in[4];
  const float* beta = (const float*)d_in[5];
  float* out = (float*)d_out;

  float* ws = (float*)d_ws;
  const size_t SZ = (size_t)B_ * H_ * N_ * HD_;  // 2M floats
  float* qw = ws;
  float* kw = ws + SZ;
  float* vw = ws + 2 * SZ;
  float* ao = ws + 3 * SZ;
  float* fc = ws + 4 * SZ;

  factor_kernel<<<B_ * N_, 64, 0, stream>>>(x, alpha, beta, fc);
  gemm_qkv_kernel<<<dim3(3 * C_ / 128, B_ * N_ / 128), 256, 0, stream>>>(
      x, wqkv, qw, kw, vw);
  attn_kernel<<<(B_ * H_ * N_) / 16, 256, 0, stream>>>(qw, kw, vw, fc, ao);
  gemm_out_kernel<<<dim3(C_ / 128, B_ * N_ / 128), 256, 0, stream>>>(
      ao, wout, bout, out);
}

// Round 4
// 706.717 us; speedup vs baseline: 3.4085x; 1.0392x over previous
//
#include <hip/hip_runtime.h>

#define B_ 2
#define N_ 1024
#define C_ 1024
#define H_ 16
#define HD_ 64

// ---------- wave-wide (64-lane) helpers ----------
__device__ __forceinline__ float wsumf(float x) {
#pragma unroll
  for (int off = 32; off; off >>= 1) x += __shfl_xor(x, off, 64);
  return x;
}
// order-preserving float->uint map (total order matches float compare for non-NaN)
__device__ __forceinline__ unsigned orderu(float f) {
  unsigned b = __float_as_uint(f);
  return (b & 0x80000000u) ? ~b : (b | 0x80000000u);
}
__device__ __forceinline__ float iorderu(unsigned x) {
  unsigned b = (x & 0x80000000u) ? (x & 0x7FFFFFFFu) : ~x;
  return __uint_as_float(b);
}

// ---------- NKAT per-token factor ----------
__global__ __launch_bounds__(64) void factor_kernel(
    const float* __restrict__ x, const float* __restrict__ alpha_p,
    const float* __restrict__ beta_p, float* __restrict__ fac) {
  const int row = blockIdx.x;  // b*N + n
  const int lane = threadIdx.x;
  const float4* xr = (const float4*)(x + (size_t)row * C_);
  float s = 0.f, ss = 0.f;
#pragma unroll
  for (int j = 0; j < 4; ++j) {
    float4 v = xr[lane + 64 * j];
    s += v.x + v.y + v.z + v.w;
    ss += v.x * v.x + v.y * v.y + v.z * v.z + v.w * v.w;
  }
  s = wsumf(s);
  ss = wsumf(ss);
  const float mean = s * (1.f / 1024.f);
  const float var = ss * (1.f / 1024.f) - mean * mean;
  const float theta =
      alpha_p[0] * tanhf(mean) + beta_p[0] * (1.f / (1.f + __expf(-var)));
  if (lane == 0) fac[row] = 1.f + 0.45125f * theta;  // lc = 0.5*0.95^2
}

// ---------- shared f32 GEMM core: 128x128 tile, 256 thr, 8x8/thread, BK=8 ----------
// register prefetch: tile k+1 loads issue before tile k's FMA phase
__device__ __forceinline__ void gemm_core(const float* __restrict__ A,
                                          const float* __restrict__ Bm, int K,
                                          int N, int m0, int n0,
                                          float* __restrict__ a_lds,
                                          float* __restrict__ b_lds,
                                          float acc[8][8]) {
  const int tid = threadIdx.x;
  const int tx = tid & 15, ty = tid >> 4;
  const int r = tid >> 1, c4 = (tid & 1) << 2;     // A tile: 128 rows x 8 cols
  const int rb = tid >> 5, cb = (tid & 31) << 4;   // B tile: 8 rows x 128 cols
  float4 av = *(const float4*)(A + (size_t)(m0 + r) * K + c4);
  float4 bv = *(const float4*)(Bm + (size_t)rb * N + n0 + (cb >> 2));
  for (int k0 = 0; k0 < K; k0 += 8) {
    __syncthreads();  // previous iteration's LDS reads done
    a_lds[(c4 + 0) * 128 + r] = av.x;  // store A transposed: [k][m]
    a_lds[(c4 + 1) * 128 + r] = av.y;
    a_lds[(c4 + 2) * 128 + r] = av.z;
    a_lds[(c4 + 3) * 128 + r] = av.w;
    *(float4*)(b_lds + rb * 128 + (cb >> 2)) = bv;
    __syncthreads();
    if (k0 + 8 < K) {  // prefetch next tile; latency hides under FMA phase
      av = *(const float4*)(A + (size_t)(m0 + r) * K + k0 + 8 + c4);
      bv = *(const float4*)(Bm + (size_t)(k0 + 8 + rb) * N + n0 + (cb >> 2));
    }
#pragma unroll
    for (int kk = 0; kk < 8; ++kk) {
      const float4 a0 = *(const float4*)(a_lds + kk * 128 + ty * 8);
      const float4 a1 = *(const float4*)(a_lds + kk * 128 + ty * 8 + 4);
      const float4 b0 = *(const float4*)(b_lds + kk * 128 + tx * 8);
      const float4 b1 = *(const float4*)(b_lds + kk * 128 + tx * 8 + 4);
      const float af[8] = {a0.x, a0.y, a0.z, a0.w, a1.x, a1.y, a1.z, a1.w};
      const float bf[8] = {b0.x, b0.y, b0.z, b0.w, b1.x, b1.y, b1.z, b1.w};
#pragma unroll
      for (int i = 0; i < 8; ++i)
#pragma unroll
        for (int jj = 0; jj < 8; ++jj)
          acc[i][jj] = fmaf(af[i], bf[jj], acc[i][jj]);
    }
  }
}

// ---------- qkv = x @ w_qkv, scatter into q/k/v in (B,H,N,HD) layout ----------
__global__ __launch_bounds__(256) void gemm_qkv_kernel(
    const float* __restrict__ x, const float* __restrict__ w,
    float* __restrict__ q, float* __restrict__ k, float* __restrict__ v) {
  __shared__ __align__(16) float a_lds[8 * 128];
  __shared__ __align__(16) float b_lds[8 * 128];
  float acc[8][8];
#pragma unroll
  for (int i = 0; i < 8; ++i)
#pragma unroll
    for (int jj = 0; jj < 8; ++jj) acc[i][jj] = 0.f;
  const int m0 = blockIdx.y * 128, n0 = blockIdx.x * 128;
  gemm_core(x, w, C_, 3 * C_, m0, n0, a_lds, b_lds, acc);

  const int tx = threadIdx.x & 15, ty = threadIdx.x >> 4;
  const int j0 = n0 + tx * 8;           // 8 consecutive cols: same sel, same head
  const int sel = j0 >> 10;             // 0=q 1=k 2=v
  const int hh = (j0 >> 6) & 15;
  const int d0 = j0 & 63;
  float* dstbuf = sel == 0 ? q : (sel == 1 ? k : v);
#pragma unroll
  for (int i = 0; i < 8; ++i) {
    const int mm = m0 + ty * 8 + i;
    const int bb = mm >> 10, nn = mm & 1023;
    float* dst = dstbuf + ((((size_t)bb << 4) + hh) * N_ + nn) * HD_ + d0;
    *(float4*)dst = make_float4(acc[i][0], acc[i][1], acc[i][2], acc[i][3]);
    *(float4*)(dst + 4) = make_float4(acc[i][4], acc[i][5], acc[i][6], acc[i][7]);
  }
}

// ---------- out = attn_out @ w_out + b_out ----------
__global__ __launch_bounds__(256) void gemm_out_kernel(
    const float* __restrict__ a, const float* __restrict__ w,
    const float* __restrict__ bias, float* __restrict__ out) {
  __shared__ __align__(16) float a_lds[8 * 128];
  __shared__ __align__(16) float b_lds[8 * 128];
  float acc[8][8];
#pragma unroll
  for (int i = 0; i < 8; ++i)
#pragma unroll
    for (int jj = 0; jj < 8; ++jj) acc[i][jj] = 0.f;
  const int m0 = blockIdx.y * 128, n0 = blockIdx.x * 128;
  gemm_core(a, w, C_, C_, m0, n0, a_lds, b_lds, acc);

  const int tx = threadIdx.x & 15, ty = threadIdx.x >> 4;
  const int j0 = n0 + tx * 8;
  const float4 bs0 = *(const float4*)(bias + j0);
  const float4 bs1 = *(const float4*)(bias + j0 + 4);
#pragma unroll
  for (int i = 0; i < 8; ++i) {
    const int mm = m0 + ty * 8 + i;
    float* dst = out + (size_t)mm * C_ + j0;
    *(float4*)dst = make_float4(acc[i][0] + bs0.x, acc[i][1] + bs0.y,
                                acc[i][2] + bs0.z, acc[i][3] + bs0.w);
    *(float4*)(dst + 4) = make_float4(acc[i][4] + bs1.x, acc[i][5] + bs1.y,
                                      acc[i][6] + bs1.z, acc[i][7] + bs1.w);
  }
}

// ---------- attention: 4 waves/block, 4 queries/wave ----------
// All LDS is wave-private ([wid]-sliced): NO block barriers anywhere — DS ops
// from one wave complete in order, waves run decoupled.
// top-k: 4 queries' ballot-count binary searches batched (4-way ILP on the
// serial chain). top-p: bitonic sort + prefix scan per query.
__global__ __launch_bounds__(256) void attn_kernel(
    const float* __restrict__ qw, const float* __restrict__ kw,
    const float* __restrict__ vw, const float* __restrict__ fac,
    float* __restrict__ ao) {
  const int lane = threadIdx.x & 63;
  const int wid = threadIdx.x >> 6;
  const int qblk = blockIdx.x * 16;      // 16 queries per block, same (b,h)
  const int bh = qblk >> 10;
  const int b = bh >> 4, h = bh & 15;
  const int q0 = (qblk & (N_ - 1)) + wid * 4;  // first query of this wave

  __shared__ __align__(16) float q_lds[4][4][HD_];
  __shared__ unsigned su[4][64];
  __shared__ float sv[4][64];
  __shared__ int ck[4][64];
  __shared__ float cv[4][64];

  // load this wave's 4 query vectors (each lane: one float4); wave-private,
  // DS in-order within a wave -> no barrier needed
  {
    const int qq = lane >> 4, dp = (lane & 15) << 2;
    *(float4*)(&q_lds[wid][qq][dp]) =
        *(const float4*)(qw + ((size_t)bh * N_ + q0 + qq) * HD_ + dp);
  }

  const float* kb = kw + ((size_t)bh << 16);
  const unsigned long long ltmask = (1ull << lane) - 1ull;
  unsigned u[4][16];  // [query][j], persistent selection state

  // ---- score phase: j-tiled so K rows stream through L1, q from LDS ----
  for (int jt = 0; jt < 4; ++jt) {
    float acc[4][4];  // [jl][query]
#pragma unroll
    for (int a = 0; a < 4; ++a)
#pragma unroll
      for (int c = 0; c < 4; ++c) acc[a][c] = 0.f;
#pragma unroll 2
    for (int dd2 = 0; dd2 < 16; ++dd2) {
      float4 qv[4];
#pragma unroll
      for (int q = 0; q < 4; ++q)
        qv[q] = *(const float4*)(&q_lds[wid][q][dd2 << 2]);
#pragma unroll
      for (int jl = 0; jl < 4; ++jl) {
        const int key = lane + (((jt << 2) + jl) << 6);
        const float4 kv =
            *(const float4*)(kb + ((size_t)key << 6) + (dd2 << 2));
#pragma unroll
        for (int q = 0; q < 4; ++q) {
          acc[jl][q] = fmaf(kv.x, qv[q].x, acc[jl][q]);
          acc[jl][q] = fmaf(kv.y, qv[q].y, acc[jl][q]);
          acc[jl][q] = fmaf(kv.z, qv[q].z, acc[jl][q]);
          acc[jl][q] = fmaf(kv.w, qv[q].w, acc[jl][q]);
        }
      }
    }
#pragma unroll
    for (int jl = 0; jl < 4; ++jl)
#pragma unroll
      for (int q = 0; q < 4; ++q)
        u[q][(jt << 2) + jl] = orderu((acc[jl][q] * 0.125f) / 0.8f);
  }

  // ---- batched wave-max over 4 queries (integer max == float max) ----
  unsigned mu[4];
#pragma unroll
  for (int q = 0; q < 4; ++q) {
    unsigned mq = u[q][0];
#pragma unroll
    for (int j = 1; j < 16; ++j) mq = max(mq, u[q][j]);
    mu[q] = mq;
  }
#pragma unroll
  for (int off = 32; off; off >>= 1) {
#pragma unroll
    for (int q = 0; q < 4; ++q)
      mu[q] = max(mu[q], (unsigned)__shfl_xor((int)mu[q], off, 64));
  }

  // ---- batched top-k binary searches (4 independent chains, lockstep) ----
  // kth[q] = largest t with count(u[q] >= t) >= 64
  unsigned lo[4], hi[4];
#pragma unroll
  for (int q = 0; q < 4; ++q) { lo[q] = 0u; hi[q] = mu[q]; }
  while ((lo[0] < hi[0]) | (lo[1] < hi[1]) | (lo[2] < hi[2]) |
         (lo[3] < hi[3])) {
#pragma unroll
    for (int q = 0; q < 4; ++q) {
      if (lo[q] < hi[q]) {  // wave-uniform condition
        const unsigned mid = lo[q] + ((hi[q] - lo[q]) >> 1) + 1u;
        int c = 0;
#pragma unroll
        for (int j = 0; j < 16; ++j)
          c += (int)__popcll(__ballot(u[q][j] >= mid));
        if (c >= 64) lo[q] = mid; else hi[q] = mid - 1u;
      }
    }
  }

  // ---- per-query: top-p + softmax + PV ----
  const float* vb = vw + ((size_t)bh << 16);
#pragma unroll
  for (int qq = 0; qq < 4; ++qq) {
    const unsigned kthu = lo[qq];
    const float m = iorderu(mu[qq]);

    // exp over kept set (others exactly 0 = exp(NEG-m) underflow)
    float e[16];
    float zl = 0.f;
#pragma unroll
    for (int j = 0; j < 16; ++j) {
      const float ej = (u[qq][j] >= kthu) ? expf(iorderu(u[qq][j]) - m) : 0.f;
      e[j] = ej;
      zl += ej;
    }
    const float Z = wsumf(zl);
    const float limit = 0.9f * Z;  // TOP_P * Z

    // compact survivors (u>=kth; count >= 64 always, so slots 0..63 all fill)
    int base = 0;
#pragma unroll
    for (int j = 0; j < 16; ++j) {
      const bool f = (u[qq][j] >= kthu);
      const unsigned long long mb = __ballot(f);
      if (f) {
        const int pos = base + (int)__popcll(mb & ltmask);
        if (pos < 64) {
          su[wid][pos] = u[qq][j];
          sv[wid][pos] = e[j];
        }
      }
      base += (int)__popcll(mb);
    }

    // bitonic sort across 64 lanes, ascending by ~u (= descending by u)
    unsigned sk = ~su[wid][lane];
    float se = sv[wid][lane];
#pragma unroll
    for (int k = 2; k <= 64; k <<= 1) {
#pragma unroll
      for (int j = k >> 1; j; j >>= 1) {
        const unsigned pk = (unsigned)__shfl_xor((int)sk, j, 64);
        const float pe = __shfl_xor(se, j, 64);
        const bool takeMin = (((lane & j) == 0) == ((lane & k) == 0));
        const bool sw = takeMin ? (pk < sk) : (pk > sk);
        if (sw) { sk = pk; se = pe; }
      }
    }

    // inclusive prefix sum of e in sorted (descending-u) order
    float pre = se;
#pragma unroll
    for (int off = 1; off <= 32; off <<= 1) {
      const float t = __shfl_up(pre, off, 64);
      if (lane >= off) pre += t;
    }
    const float excl = pre - se;
    const bool keep = (excl <= limit);  // first always kept (excl==0)
    const unsigned long long km = __ballot(keep);
    const int L = 63 - __builtin_clzll(km);
    const unsigned thr = ~(unsigned)__shfl((int)sk, L, 64);  // min kept value

    // Z over final kept set (u >= thr); kept set is a subset of survivors
    float z2l = 0.f;
#pragma unroll
    for (int j = 0; j < 16; ++j) z2l += (u[qq][j] >= thr) ? e[j] : 0.f;
    const float Z2 = wsumf(z2l);
    const float wsc = fac[(b << 10) + q0 + qq] / Z2;

    // compact final kept (idx, weight) for PV; M <= 64 provably
    int M = 0;
#pragma unroll
    for (int j = 0; j < 16; ++j) {
      const bool f = (u[qq][j] >= thr);
      const unsigned long long mb = __ballot(f);
      if (f) {
        const int pos = M + (int)__popcll(mb & ltmask);
        if (pos < 64) {
          ck[wid][pos] = lane + (j << 6);
          cv[wid][pos] = e[j] * wsc;
        }
      }
      M += (int)__popcll(mb);
    }
    if (M > 64) M = 64;

    // PV over surviving keys; lane = output dim d
    float a0 = 0.f, a1 = 0.f, a2 = 0.f, a3 = 0.f;
    int i = 0;
    for (; i + 4 <= M; i += 4) {
      const int k0 = ck[wid][i], k1 = ck[wid][i + 1];
      const int k2 = ck[wid][i + 2], k3 = ck[wid][i + 3];
      const float c0 = cv[wid][i], c1 = cv[wid][i + 1];
      const float c2 = cv[wid][i + 2], c3 = cv[wid][i + 3];
      a0 = fmaf(c0, vb[((size_t)k0 << 6) + lane], a0);
      a1 = fmaf(c1, vb[((size_t)k1 << 6) + lane], a1);
      a2 = fmaf(c2, vb[((size_t)k2 << 6) + lane], a2);
      a3 = fmaf(c3, vb[((size_t)k3 << 6) + lane], a3);
    }
    for (; i < M; ++i)
      a0 = fmaf(cv[wid][i], vb[((size_t)ck[wid][i] << 6) + lane], a0);
    const float o = (a0 + a1) + (a2 + a3);

    ao[(((size_t)b << 10) + q0 + qq) * C_ + (h << 6) + lane] = o;
  }
}

extern "C" void kernel_launch(void* const* d_in, const int* in_sizes, int n_in,
                              void* d_out, int out_size, void* d_ws,
                              size_t ws_size, hipStream_t stream) {
  const float* x = (const float*)d_in[0];
  const float* wqkv = (const float*)d_in[1];
  const float* wout = (const float*)d_in[2];
  const float* bout = (const float*)d_in[3];
  const float* alpha = (const float*)d_in[4];
  const float* beta = (const float*)d_in[5];
  float* out = (float*)d_out;

  float* ws = (float*)d_ws;
  const size_t SZ = (size_t)B_ * H_ * N_ * HD_;  // 2M floats
  float* qw = ws;
  float* kw = ws + SZ;
  float* vw = ws + 2 * SZ;
  float* ao = ws + 3 * SZ;
  float* fc = ws + 4 * SZ;

  factor_kernel<<<B_ * N_, 64, 0, stream>>>(x, alpha, beta, fc);
  gemm_qkv_kernel<<<dim3(3 * C_ / 128, B_ * N_ / 128), 256, 0, stream>>>(
      x, wqkv, qw, kw, vw);
  attn_kernel<<<(B_ * H_ * N_) / 16, 256, 0, stream>>>(qw, kw, vw, fc, ao);
  gemm_out_kernel<<<dim3(C_ / 128, B_ * N_ / 128), 256, 0, stream>>>(
      ao, wout, bout, out);
}

// Round 5
// 561.134 us; speedup vs baseline: 4.2928x; 1.2594x over previous
//
#include <hip/hip_runtime.h>

#define B_ 2
#define N_ 1024
#define C_ 1024
#define H_ 16
#define HD_ 64

// ---------- wave-wide (64-lane) helpers ----------
__device__ __forceinline__ float wsumf(float x) {
#pragma unroll
  for (int off = 32; off; off >>= 1) x += __shfl_xor(x, off, 64);
  return x;
}
// order-preserving float->uint map (total order matches float compare for non-NaN)
__device__ __forceinline__ unsigned orderu(float f) {
  unsigned b = __float_as_uint(f);
  return (b & 0x80000000u) ? ~b : (b | 0x80000000u);
}
__device__ __forceinline__ float iorderu(unsigned x) {
  unsigned b = (x & 0x80000000u) ? (x & 0x7FFFFFFFu) : ~x;
  return __uint_as_float(b);
}

// ---------- NKAT per-token factor ----------
__global__ __launch_bounds__(64) void factor_kernel(
    const float* __restrict__ x, const float* __restrict__ alpha_p,
    const float* __restrict__ beta_p, float* __restrict__ fac) {
  const int row = blockIdx.x;  // b*N + n
  const int lane = threadIdx.x;
  const float4* xr = (const float4*)(x + (size_t)row * C_);
  float s = 0.f, ss = 0.f;
#pragma unroll
  for (int j = 0; j < 4; ++j) {
    float4 v = xr[lane + 64 * j];
    s += v.x + v.y + v.z + v.w;
    ss += v.x * v.x + v.y * v.y + v.z * v.z + v.w * v.w;
  }
  s = wsumf(s);
  ss = wsumf(ss);
  const float mean = s * (1.f / 1024.f);
  const float var = ss * (1.f / 1024.f) - mean * mean;
  const float theta =
      alpha_p[0] * tanhf(mean) + beta_p[0] * (1.f / (1.f + __expf(-var)));
  if (lane == 0) fac[row] = 1.f + 0.45125f * theta;  // lc = 0.5*0.95^2
}

// ---------- shared f32 GEMM core: 128x128 tile, 256 thr, 8x8/thread, BK=8 ----------
__device__ __forceinline__ void gemm_core(const float* __restrict__ A,
                                          const float* __restrict__ Bm, int K,
                                          int N, int m0, int n0,
                                          float* __restrict__ a_lds,
                                          float* __restrict__ b_lds,
                                          float acc[8][8]) {
  const int tid = threadIdx.x;
  const int tx = tid & 15, ty = tid >> 4;
  const int r = tid >> 1, c4 = (tid & 1) << 2;     // A tile: 128 rows x 8 cols
  const int rb = tid >> 5, cb = (tid & 31) << 2;   // B tile: 8 rows x 128 cols
  float4 av = *(const float4*)(A + (size_t)(m0 + r) * K + c4);
  float4 bv = *(const float4*)(Bm + (size_t)rb * N + n0 + cb);
  for (int k0 = 0; k0 < K; k0 += 8) {
    __syncthreads();  // previous iteration's LDS reads done
    a_lds[(c4 + 0) * 128 + r] = av.x;  // store A transposed: [k][m]
    a_lds[(c4 + 1) * 128 + r] = av.y;
    a_lds[(c4 + 2) * 128 + r] = av.z;
    a_lds[(c4 + 3) * 128 + r] = av.w;
    *(float4*)(b_lds + rb * 128 + cb) = bv;
    __syncthreads();
    if (k0 + 8 < K) {  // prefetch next tile; latency hides under FMA phase
      av = *(const float4*)(A + (size_t)(m0 + r) * K + k0 + 8 + c4);
      bv = *(const float4*)(Bm + (size_t)(k0 + 8 + rb) * N + n0 + cb);
    }
#pragma unroll
    for (int kk = 0; kk < 8; ++kk) {
      const float4 a0 = *(const float4*)(a_lds + kk * 128 + ty * 8);
      const float4 a1 = *(const float4*)(a_lds + kk * 128 + ty * 8 + 4);
      const float4 b0 = *(const float4*)(b_lds + kk * 128 + tx * 8);
      const float4 b1 = *(const float4*)(b_lds + kk * 128 + tx * 8 + 4);
      const float af[8] = {a0.x, a0.y, a0.z, a0.w, a1.x, a1.y, a1.z, a1.w};
      const float bf[8] = {b0.x, b0.y, b0.z, b0.w, b1.x, b1.y, b1.z, b1.w};
#pragma unroll
      for (int i = 0; i < 8; ++i)
#pragma unroll
        for (int jj = 0; jj < 8; ++jj)
          acc[i][jj] = fmaf(af[i], bf[jj], acc[i][jj]);
    }
  }
}

// ---------- qkv = x @ w_qkv; Q,V in (B,H,N,HD); K TRANSPOSED: kt[bh][d][n] ----------
__global__ __launch_bounds__(256) void gemm_qkv_kernel(
    const float* __restrict__ x, const float* __restrict__ w,
    float* __restrict__ q, float* __restrict__ kt, float* __restrict__ v) {
  __shared__ __align__(16) float a_lds[8 * 128];
  __shared__ __align__(16) float b_lds[8 * 128];
  float acc[8][8];
#pragma unroll
  for (int i = 0; i < 8; ++i)
#pragma unroll
    for (int jj = 0; jj < 8; ++jj) acc[i][jj] = 0.f;
  const int m0 = blockIdx.y * 128, n0 = blockIdx.x * 128;
  gemm_core(x, w, C_, 3 * C_, m0, n0, a_lds, b_lds, acc);

  const int tx = threadIdx.x & 15, ty = threadIdx.x >> 4;
  const int j0 = n0 + tx * 8;           // 8 consecutive cols: same sel, same head
  const int sel = j0 >> 10;             // 0=q 1=k 2=v
  const int hh = (j0 >> 6) & 15;
  const int d0 = j0 & 63;
  const int bb = m0 >> 10;              // whole 128-row stripe in same batch
  const int nn0 = (m0 & 1023) + ty * 8; // rows nn0..nn0+7 consecutive

  if (sel == 1) {
    // K transposed: kt[((bb*16+hh)*64 + d)*1024 + n]; rows i are consecutive n
#pragma unroll
    for (int jj = 0; jj < 8; ++jj) {
      float* dst = kt + (((size_t)((bb << 4) + hh) * HD_ + d0 + jj) * N_ + nn0);
      *(float4*)dst = make_float4(acc[0][jj], acc[1][jj], acc[2][jj], acc[3][jj]);
      *(float4*)(dst + 4) =
          make_float4(acc[4][jj], acc[5][jj], acc[6][jj], acc[7][jj]);
    }
  } else {
    float* dstbuf = (sel == 0) ? q : v;
#pragma unroll
    for (int i = 0; i < 8; ++i) {
      float* dst = dstbuf + ((((size_t)(bb << 4)) + hh) * N_ + nn0 + i) * HD_ + d0;
      *(float4*)dst = make_float4(acc[i][0], acc[i][1], acc[i][2], acc[i][3]);
      *(float4*)(dst + 4) =
          make_float4(acc[i][4], acc[i][5], acc[i][6], acc[i][7]);
    }
  }
}

// ---------- out = attn_out @ w_out + b_out ----------
__global__ __launch_bounds__(256) void gemm_out_kernel(
    const float* __restrict__ a, const float* __restrict__ w,
    const float* __restrict__ bias, float* __restrict__ out) {
  __shared__ __align__(16) float a_lds[8 * 128];
  __shared__ __align__(16) float b_lds[8 * 128];
  float acc[8][8];
#pragma unroll
  for (int i = 0; i < 8; ++i)
#pragma unroll
    for (int jj = 0; jj < 8; ++jj) acc[i][jj] = 0.f;
  const int m0 = blockIdx.y * 128, n0 = blockIdx.x * 128;
  gemm_core(a, w, C_, C_, m0, n0, a_lds, b_lds, acc);

  const int tx = threadIdx.x & 15, ty = threadIdx.x >> 4;
  const int j0 = n0 + tx * 8;
  const float4 bs0 = *(const float4*)(bias + j0);
  const float4 bs1 = *(const float4*)(bias + j0 + 4);
#pragma unroll
  for (int i = 0; i < 8; ++i) {
    const int mm = m0 + ty * 8 + i;
    float* dst = out + (size_t)mm * C_ + j0;
    *(float4*)dst = make_float4(acc[i][0] + bs0.x, acc[i][1] + bs0.y,
                                acc[i][2] + bs0.z, acc[i][3] + bs0.w);
    *(float4*)(dst + 4) = make_float4(acc[i][4] + bs1.x, acc[i][5] + bs1.y,
                                      acc[i][6] + bs1.z, acc[i][7] + bs1.w);
  }
}

// ---------- attention: 4 waves/block, 4 queries/wave; coalesced K^T scores ----------
// key = pass*256 + lane*4 + jl ; u[q][pass*4+jl] is the selection state.
// Per d: one contiguous 1KB wave load of kt row-segment + broadcast q read.
__global__ __launch_bounds__(256) void attn_kernel(
    const float* __restrict__ qw, const float* __restrict__ kt,
    const float* __restrict__ vw, const float* __restrict__ fac,
    float* __restrict__ ao) {
  const int lane = threadIdx.x & 63;
  const int wid = threadIdx.x >> 6;
  const int qblk = blockIdx.x * 16;      // 16 queries per block, same (b,h)
  const int bh = qblk >> 10;
  const int b = bh >> 4, h = bh & 15;
  const int q0 = (qblk & (N_ - 1)) + wid * 4;  // first query of this wave

  __shared__ __align__(16) float q_ldsT[4][HD_][4];  // [wave][d][query]
  __shared__ unsigned su[4][64];
  __shared__ float sv[4][64];
  __shared__ int ck[4][64];
  __shared__ float cv[4][64];

  // load this wave's 4 query vectors, store transposed [d][q]; wave-private,
  // DS ops in-order within a wave -> no barrier needed
  {
    const int qq = lane >> 4, dp = (lane & 15) << 2;
    const float4 v =
        *(const float4*)(qw + ((size_t)bh * N_ + q0 + qq) * HD_ + dp);
    q_ldsT[wid][dp + 0][qq] = v.x;
    q_ldsT[wid][dp + 1][qq] = v.y;
    q_ldsT[wid][dp + 2][qq] = v.z;
    q_ldsT[wid][dp + 3][qq] = v.w;
  }

  const float* ktb = kt + ((size_t)bh * HD_ * N_);  // [d][n]
  const unsigned long long ltmask = (1ull << lane) - 1ull;
  unsigned u[4][16];  // [query][pass*4+jl]

  // ---- score phase: fully-coalesced K^T streaming ----
  for (int pass = 0; pass < 4; ++pass) {
    float acc[4][4];  // [jl][query]
#pragma unroll
    for (int a = 0; a < 4; ++a)
#pragma unroll
      for (int c = 0; c < 4; ++c) acc[a][c] = 0.f;
    const float* kp = ktb + (pass << 8) + (lane << 2);
#pragma unroll 4
    for (int d = 0; d < HD_; ++d) {
      const float4 kv = *(const float4*)(kp + (size_t)d * N_);
      const float4 qv = *(const float4*)(&q_ldsT[wid][d][0]);  // broadcast
      acc[0][0] = fmaf(kv.x, qv.x, acc[0][0]);
      acc[0][1] = fmaf(kv.x, qv.y, acc[0][1]);
      acc[0][2] = fmaf(kv.x, qv.z, acc[0][2]);
      acc[0][3] = fmaf(kv.x, qv.w, acc[0][3]);
      acc[1][0] = fmaf(kv.y, qv.x, acc[1][0]);
      acc[1][1] = fmaf(kv.y, qv.y, acc[1][1]);
      acc[1][2] = fmaf(kv.y, qv.z, acc[1][2]);
      acc[1][3] = fmaf(kv.y, qv.w, acc[1][3]);
      acc[2][0] = fmaf(kv.z, qv.x, acc[2][0]);
      acc[2][1] = fmaf(kv.z, qv.y, acc[2][1]);
      acc[2][2] = fmaf(kv.z, qv.z, acc[2][2]);
      acc[2][3] = fmaf(kv.z, qv.w, acc[2][3]);
      acc[3][0] = fmaf(kv.w, qv.x, acc[3][0]);
      acc[3][1] = fmaf(kv.w, qv.y, acc[3][1]);
      acc[3][2] = fmaf(kv.w, qv.z, acc[3][2]);
      acc[3][3] = fmaf(kv.w, qv.w, acc[3][3]);
    }
#pragma unroll
    for (int jl = 0; jl < 4; ++jl)
#pragma unroll
      for (int q = 0; q < 4; ++q)
        u[q][(pass << 2) + jl] = orderu((acc[jl][q] * 0.125f) / 0.8f);
  }

  // ---- batched wave-max over 4 queries (integer max == float max) ----
  unsigned mu[4];
#pragma unroll
  for (int q = 0; q < 4; ++q) {
    unsigned mq = u[q][0];
#pragma unroll
    for (int j = 1; j < 16; ++j) mq = max(mq, u[q][j]);
    mu[q] = mq;
  }
#pragma unroll
  for (int off = 32; off; off >>= 1) {
#pragma unroll
    for (int q = 0; q < 4; ++q)
      mu[q] = max(mu[q], (unsigned)__shfl_xor((int)mu[q], off, 64));
  }

  // ---- batched top-k binary searches (4 independent chains, lockstep) ----
  unsigned lo[4], hi[4];
#pragma unroll
  for (int q = 0; q < 4; ++q) { lo[q] = 0u; hi[q] = mu[q]; }
  while ((lo[0] < hi[0]) | (lo[1] < hi[1]) | (lo[2] < hi[2]) |
         (lo[3] < hi[3])) {
#pragma unroll
    for (int q = 0; q < 4; ++q) {
      if (lo[q] < hi[q]) {  // wave-uniform condition
        const unsigned mid = lo[q] + ((hi[q] - lo[q]) >> 1) + 1u;
        int c = 0;
#pragma unroll
        for (int j = 0; j < 16; ++j)
          c += (int)__popcll(__ballot(u[q][j] >= mid));
        if (c >= 64) lo[q] = mid; else hi[q] = mid - 1u;
      }
    }
  }

  // ---- per-query: top-p + softmax + PV ----
  const float* vb = vw + ((size_t)bh << 16);
#pragma unroll
  for (int qq = 0; qq < 4; ++qq) {
    const unsigned kthu = lo[qq];
    const float m = iorderu(mu[qq]);

    // exp over kept set (others exactly 0 = exp(NEG-m) underflow)
    float e[16];
    float zl = 0.f;
#pragma unroll
    for (int j = 0; j < 16; ++j) {
      const float ej = (u[qq][j] >= kthu) ? expf(iorderu(u[qq][j]) - m) : 0.f;
      e[j] = ej;
      zl += ej;
    }
    const float Z = wsumf(zl);
    const float limit = 0.9f * Z;  // TOP_P * Z

    // compact survivors (u>=kth; count >= 64 always, so slots 0..63 all fill)
    int base = 0;
#pragma unroll
    for (int j = 0; j < 16; ++j) {
      const bool f = (u[qq][j] >= kthu);
      const unsigned long long mb = __ballot(f);
      if (f) {
        const int pos = base + (int)__popcll(mb & ltmask);
        if (pos < 64) {
          su[wid][pos] = u[qq][j];
          sv[wid][pos] = e[j];
        }
      }
      base += (int)__popcll(mb);
    }

    // bitonic sort across 64 lanes, ascending by ~u (= descending by u)
    unsigned sk = ~su[wid][lane];
    float se = sv[wid][lane];
#pragma unroll
    for (int k = 2; k <= 64; k <<= 1) {
#pragma unroll
      for (int j = k >> 1; j; j >>= 1) {
        const unsigned pk = (unsigned)__shfl_xor((int)sk, j, 64);
        const float pe = __shfl_xor(se, j, 64);
        const bool takeMin = (((lane & j) == 0) == ((lane & k) == 0));
        const bool sw = takeMin ? (pk < sk) : (pk > sk);
        if (sw) { sk = pk; se = pe; }
      }
    }

    // inclusive prefix sum of e in sorted (descending-u) order
    float pre = se;
#pragma unroll
    for (int off = 1; off <= 32; off <<= 1) {
      const float t = __shfl_up(pre, off, 64);
      if (lane >= off) pre += t;
    }
    const float excl = pre - se;
    const bool keep = (excl <= limit);  // first always kept (excl==0)
    const unsigned long long km = __ballot(keep);
    const int L = 63 - __builtin_clzll(km);
    const unsigned thr = ~(unsigned)__shfl((int)sk, L, 64);  // min kept value

    // Z over final kept set (u >= thr)
    float z2l = 0.f;
#pragma unroll
    for (int j = 0; j < 16; ++j) z2l += (u[qq][j] >= thr) ? e[j] : 0.f;
    const float Z2 = wsumf(z2l);
    const float wsc = fac[(b << 10) + q0 + qq] / Z2;

    // compact final kept (idx, weight) for PV; M <= 64 provably
    int M = 0;
#pragma unroll
    for (int j = 0; j < 16; ++j) {
      const bool f = (u[qq][j] >= thr);
      const unsigned long long mb = __ballot(f);
      if (f) {
        const int pos = M + (int)__popcll(mb & ltmask);
        if (pos < 64) {
          // key = pass*256 + lane*4 + jl, with j = pass*4 + jl
          ck[wid][pos] = ((j >> 2) << 8) + (lane << 2) + (j & 3);
          cv[wid][pos] = e[j] * wsc;
        }
      }
      M += (int)__popcll(mb);
    }
    if (M > 64) M = 64;

    // PV over surviving keys; lane = output dim d
    float a0 = 0.f, a1 = 0.f, a2 = 0.f, a3 = 0.f;
    int i = 0;
    for (; i + 4 <= M; i += 4) {
      const int k0 = ck[wid][i], k1 = ck[wid][i + 1];
      const int k2 = ck[wid][i + 2], k3 = ck[wid][i + 3];
      const float c0 = cv[wid][i], c1 = cv[wid][i + 1];
      const float c2 = cv[wid][i + 2], c3 = cv[wid][i + 3];
      a0 = fmaf(c0, vb[((size_t)k0 << 6) + lane], a0);
      a1 = fmaf(c1, vb[((size_t)k1 << 6) + lane], a1);
      a2 = fmaf(c2, vb[((size_t)k2 << 6) + lane], a2);
      a3 = fmaf(c3, vb[((size_t)k3 << 6) + lane], a3);
    }
    for (; i < M; ++i)
      a0 = fmaf(cv[wid][i], vb[((size_t)ck[wid][i] << 6) + lane], a0);
    const float o = (a0 + a1) + (a2 + a3);

    ao[(((size_t)b << 10) + q0 + qq) * C_ + (h << 6) + lane] = o;
  }
}

extern "C" void kernel_launch(void* const* d_in, const int* in_sizes, int n_in,
                              void* d_out, int out_size, void* d_ws,
                              size_t ws_size, hipStream_t stream) {
  const float* x = (const float*)d_in[0];
  const float* wqkv = (const float*)d_in[1];
  const float* wout = (const float*)d_in[2];
  const float* bout = (const float*)d_in[3];
  const float* alpha = (const float*)d_in[4];
  const float* beta = (const float*)d_in[5];
  float* out = (float*)d_out;

  float* ws = (float*)d_ws;
  const size_t SZ = (size_t)B_ * H_ * N_ * HD_;  // 2M floats
  float* qw = ws;
  float* kt = ws + SZ;      // K stored transposed per head: [bh][d][n]
  float* vw = ws + 2 * SZ;
  float* ao = ws + 3 * SZ;
  float* fc = ws + 4 * SZ;

  factor_kernel<<<B_ * N_, 64, 0, stream>>>(x, alpha, beta, fc);
  gemm_qkv_kernel<<<dim3(3 * C_ / 128, B_ * N_ / 128), 256, 0, stream>>>(
      x, wqkv, qw, kt, vw);
  attn_kernel<<<(B_ * H_ * N_) / 16, 256, 0, stream>>>(qw, kt, vw, fc, ao);
  gemm_out_kernel<<<dim3(C_ / 128, B_ * N_ / 128), 256, 0, stream>>>(
      ao, wout, bout, out);
}